// Round 1
// baseline (668.890 us; speedup 1.0000x reference)
//
#include <hip/hip_runtime.h>
#include <cstdint>
#include <cmath>

#define DIM 4096
#define NH 32
#define NKV 8
#define HD 128
#define S_LEN 2048
#define KVD (NKV * HD)  // 1024
#define SCALE 0.08838834764831845f

typedef __attribute__((ext_vector_type(4))) float f32x4;
typedef __attribute__((ext_vector_type(8))) short short8;

__device__ __forceinline__ short f2bf(float f) {
  union { float f; uint32_t u; } v; v.f = f;
  uint32_t u = v.u;
  u += 0x7fffu + ((u >> 16) & 1u);
  return (short)(u >> 16);
}
__device__ __forceinline__ float bf2f(short b) {
  union { uint32_t u; float f; } v; v.u = ((uint32_t)(uint16_t)b) << 16;
  return v.f;
}

__device__ __forceinline__ void async16(const void* g, void* l) {
  __builtin_amdgcn_global_load_lds(
      (__attribute__((address_space(1))) void*)(g),
      (__attribute__((address_space(3))) void*)(l), 16, 0, 0);
}

// ---------------- small prep kernels ----------------

__global__ void rope_tables_k(float* __restrict__ ct, float* __restrict__ st) {
  const int i = blockIdx.x * blockDim.x + threadIdx.x;
  if (i >= S_LEN * 64) return;
  const int s = i >> 6, d = i & 63;
  const float inv = powf(10000.0f, -(float)(2 * d) / 128.0f);
  const float fr = (float)s * inv;
  ct[i] = cosf(fr);
  st[i] = sinf(fr);
}

__global__ void cast_f32_bf16_k(const float* __restrict__ in, short* __restrict__ out, int n4) {
  const int i = blockIdx.x * blockDim.x + threadIdx.x;
  if (i >= n4) return;
  const float4 v = ((const float4*)in)[i];
  short4 o;
  o.x = f2bf(v.x); o.y = f2bf(v.y); o.z = f2bf(v.z); o.w = f2bf(v.w);
  ((short4*)out)[i] = o;
}

// w: [K][N] f32 row-major  ->  wt: [N][K] bf16 row-major
__global__ void transpose_cast_k(const float* __restrict__ wsrc, short* __restrict__ wt,
                                 int K, int N) {
  __shared__ float tile[32][33];
  const int tx = threadIdx.x, ty = threadIdx.y;
  const int c0 = blockIdx.x * 32, r0 = blockIdx.y * 32;
#pragma unroll
  for (int j = 0; j < 4; ++j)
    tile[ty + j * 8][tx] = wsrc[(size_t)(r0 + ty + j * 8) * N + c0 + tx];
  __syncthreads();
#pragma unroll
  for (int j = 0; j < 4; ++j)
    wt[(size_t)(c0 + ty + j * 8) * K + r0 + tx] = f2bf(tile[tx][ty + j * 8]);
}

// in-place RoPE on bf16 [S][nheads*HD]; thread handles (d, d+64) pair
__global__ void rope_apply_k(short* __restrict__ xq, const float* __restrict__ ct,
                             const float* __restrict__ st, int nheads) {
  const int i = blockIdx.x * blockDim.x + threadIdx.x;
  const int total = S_LEN * nheads * 64;
  if (i >= total) return;
  const int d = i & 63;
  const int t = i >> 6;
  const int hh = t % nheads;
  const int s = t / nheads;
  short* p = xq + (size_t)s * (nheads * HD) + hh * HD + d;
  const float x1 = bf2f(p[0]);
  const float x2 = bf2f(p[64]);
  const float c = ct[(s << 6) + d];
  const float sn = st[(s << 6) + d];
  p[0]  = f2bf(x1 * c - x2 * sn);
  p[64] = f2bf(x2 * c + x1 * sn);
}

// ---------------- GEMM: C[M][N] = A[M][K] * BT[N][K]^T (bf16 in, fp32 acc) ----------------
// m97 structure: 128x128 tile, BK=32, global_load_lds width-16, 4 waves (2x2), 4x4 frags/wave.

template <int OUT_BF16>
__global__ __launch_bounds__(256) void gemm_bt_k(
    const short* __restrict__ A, const short* __restrict__ BT,
    void* __restrict__ Cv, int M, int N, int K) {
  __shared__ __attribute__((aligned(16))) short As[128 * 32];
  __shared__ __attribute__((aligned(16))) short Bs[128 * 32];
  const int tid = threadIdx.x;
  const int w = tid >> 6, l = tid & 63;
  const int m0 = blockIdx.x * 128, n0 = blockIdx.y * 128;
  const int wr = (w >> 1) * 64, wc = (w & 1) * 64;
  const int lrow = l & 15, lk = (l >> 4) << 3;

  f32x4 acc[4][4] = {};

  const int c0 = w * 2;
  for (int k0 = 0; k0 < K; k0 += 32) {
#pragma unroll
    for (int i = 0; i < 2; ++i) {
      const int e = (c0 + i) * 512 + l * 8;  // element index in 128x32 tile
      const int row = e >> 5, kk = e & 31;
      async16(A + (size_t)(m0 + row) * K + k0 + kk, As + e);
      async16(BT + (size_t)(n0 + row) * K + k0 + kk, Bs + e);
    }
    __syncthreads();
    short8 af[4], bfr[4];
#pragma unroll
    for (int m = 0; m < 4; ++m)
      af[m] = *(const short8*)(As + (wr + m * 16 + lrow) * 32 + lk);
#pragma unroll
    for (int n = 0; n < 4; ++n)
      bfr[n] = *(const short8*)(Bs + (wc + n * 16 + lrow) * 32 + lk);
#pragma unroll
    for (int m = 0; m < 4; ++m)
#pragma unroll
      for (int n = 0; n < 4; ++n)
        acc[m][n] = __builtin_amdgcn_mfma_f32_16x16x32_bf16(af[m], bfr[n], acc[m][n], 0, 0, 0);
    __syncthreads();
  }

  const int orow = m0 + wr + ((l >> 4) << 2);
  const int ocol = n0 + wc + lrow;
#pragma unroll
  for (int m = 0; m < 4; ++m)
#pragma unroll
    for (int n = 0; n < 4; ++n)
#pragma unroll
      for (int r = 0; r < 4; ++r) {
        const size_t idx = (size_t)(orow + m * 16 + r) * N + (ocol + n * 16);
        if (OUT_BF16)
          ((short*)Cv)[idx] = f2bf(acc[m][n][r]);
        else
          ((float*)Cv)[idx] = acc[m][n][r];
      }
}

// ---------------- flash attention (causal, GQA 4:1) ----------------
// grid: (S/64, NH). 4 waves/block; wave w owns q-rows qt*64+w*16 .. +15, full 128-d output.

__global__ __launch_bounds__(256) void attn_k(
    const short* __restrict__ Q, const short* __restrict__ Kc,
    const short* __restrict__ Vc, short* __restrict__ O) {
  __shared__ __attribute__((aligned(16))) short Ks[64 * 128];   // swizzled row-major
  __shared__ __attribute__((aligned(16))) short Vt[128 * 72];   // transposed [d][k], pad 8
  __shared__ __attribute__((aligned(16))) short Ps[4][16 * 72]; // per-wave P, pad 8

  const int tid = threadIdx.x;
  const int w = tid >> 6, l = tid & 63;
  const int qt = blockIdx.x, h = blockIdx.y, kvh = h >> 2;
  const int lrow = l & 15, lg = l >> 4, lk = lg << 3;

  // Q fragments (A-operand): lane reads row (l&15), 8 contiguous head-dims at lk
  const short* qp = Q + (size_t)(qt * 64 + w * 16 + lrow) * DIM + h * HD;
  short8 qf[4];
#pragma unroll
  for (int c = 0; c < 4; ++c) qf[c] = *(const short8*)(qp + c * 32 + lk);

  f32x4 o_acc[8] = {};
  float mrow[4] = {-INFINITY, -INFINITY, -INFINITY, -INFINITY};
  float lsum[4] = {0.f, 0.f, 0.f, 0.f};

  char* ksb = (char*)Ks;

  for (int kt = 0; kt <= qt; ++kt) {
    const int kb = kt * 64;
    // stage K tile [64][128] with XOR swizzle (kills the 32-way D=128 conflict)
#pragma unroll
    for (int it = 0; it < 4; ++it) {
      const int lin = (it * 256 + tid) * 16;  // byte index
      const int row = lin >> 8, colb = lin & 255;
      short8 d8 = *(const short8*)(Kc + (size_t)(kb + row) * KVD + kvh * HD + (colb >> 1));
      *(short8*)(ksb + (lin ^ ((row & 7) << 4))) = d8;
    }
    // stage V transposed: lane = k-row (conflict-free b16 column writes)
#pragma unroll
    for (int it = 0; it < 4; ++it) {
      const int row = tid & 63;
      const int col = ((tid >> 6) + it * 4) * 8;
      short8 d8 = *(const short8*)(Vc + (size_t)(kb + row) * KVD + kvh * HD + col);
#pragma unroll
      for (int j = 0; j < 8; ++j) Vt[(col + j) * 72 + row] = d8[j];
    }
    __syncthreads();

    // S = Q K^T  (16 q-rows x 64 k-cols per wave)
    f32x4 s[4] = {};
#pragma unroll
    for (int c = 0; c < 4; ++c) {
#pragma unroll
      for (int n = 0; n < 4; ++n) {
        const int row = n * 16 + lrow;
        short8 kf = *(const short8*)(ksb + ((row * 256 + c * 64 + (lk << 1)) ^ ((row & 7) << 4)));
        s[n] = __builtin_amdgcn_mfma_f32_16x16x32_bf16(qf[c], kf, s[n], 0, 0, 0);
      }
    }

    // scale + causal mask (only diagonal tile needs the mask)
    const bool domask = (kt == qt);
#pragma unroll
    for (int n = 0; n < 4; ++n)
#pragma unroll
      for (int r = 0; r < 4; ++r) {
        float v = s[n][r] * SCALE;
        if (domask) {
          const int qr = qt * 64 + w * 16 + lg * 4 + r;
          const int kcidx = kb + n * 16 + lrow;
          if (kcidx > qr) v = -INFINITY;
        }
        s[n][r] = v;
      }

    // online softmax; row r lives in 16-lane group lg (shfl_xor 1/2/4/8 stays in-group)
#pragma unroll
    for (int r = 0; r < 4; ++r) {
      float vmax = fmaxf(fmaxf(s[0][r], s[1][r]), fmaxf(s[2][r], s[3][r]));
      vmax = fmaxf(vmax, __shfl_xor(vmax, 1));
      vmax = fmaxf(vmax, __shfl_xor(vmax, 2));
      vmax = fmaxf(vmax, __shfl_xor(vmax, 4));
      vmax = fmaxf(vmax, __shfl_xor(vmax, 8));
      const float mnew = fmaxf(mrow[r], vmax);
      const float al = __expf(mrow[r] - mnew);
      mrow[r] = mnew;
      float rs = 0.f;
#pragma unroll
      for (int n = 0; n < 4; ++n) {
        const float p = __expf(s[n][r] - mnew);
        s[n][r] = p;
        rs += p;
      }
      rs += __shfl_xor(rs, 1); rs += __shfl_xor(rs, 2);
      rs += __shfl_xor(rs, 4); rs += __shfl_xor(rs, 8);
      lsum[r] = lsum[r] * al + rs;
#pragma unroll
      for (int d = 0; d < 8; ++d) o_acc[d][r] *= al;
    }

    // P -> LDS (bf16) to redistribute into A-fragment layout
#pragma unroll
    for (int n = 0; n < 4; ++n)
#pragma unroll
      for (int r = 0; r < 4; ++r)
        Ps[w][(lg * 4 + r) * 72 + n * 16 + lrow] = f2bf(s[n][r]);
    __syncthreads();

    // O += P V
#pragma unroll
    for (int cc = 0; cc < 2; ++cc) {
      short8 pf = *(const short8*)(&Ps[w][lrow * 72 + cc * 32 + lk]);
#pragma unroll
      for (int d = 0; d < 8; ++d) {
        short8 vf = *(const short8*)(&Vt[(d * 16 + lrow) * 72 + cc * 32 + lk]);
        o_acc[d] = __builtin_amdgcn_mfma_f32_16x16x32_bf16(pf, vf, o_acc[d], 0, 0, 0);
      }
    }
    __syncthreads();
  }

  // epilogue: O /= lsum, write bf16 [S][NH*HD]
  short* op = O + (size_t)(qt * 64 + w * 16) * DIM + h * HD;
  float inv[4];
#pragma unroll
  for (int r = 0; r < 4; ++r) inv[r] = 1.0f / lsum[r];
#pragma unroll
  for (int d = 0; d < 8; ++d)
#pragma unroll
    for (int r = 0; r < 4; ++r)
      op[(size_t)(lg * 4 + r) * DIM + d * 16 + lrow] = f2bf(o_acc[d][r] * inv[r]);
}

// ---------------- launch ----------------

extern "C" void kernel_launch(void* const* d_in, const int* in_sizes, int n_in,
                              void* d_out, int out_size, void* d_ws, size_t ws_size,
                              hipStream_t stream) {
  const float* x  = (const float*)d_in[0];
  const float* wq = (const float*)d_in[1];
  const float* wk = (const float*)d_in[2];
  const float* wv = (const float*)d_in[3];
  const float* wo = (const float*)d_in[4];
  float* out = (float*)d_out;
  (void)in_sizes; (void)n_in; (void)out_size; (void)ws_size;

  char* ws = (char*)d_ws;
  size_t off = 0;
  auto alloc = [&](size_t bytes) -> void* {
    void* p = ws + off;
    off += (bytes + 255) & ~(size_t)255;
    return p;
  };
  short* xb  = (short*)alloc((size_t)S_LEN * DIM * 2);
  short* wqT = (short*)alloc((size_t)DIM * DIM * 2);
  short* wkT = (short*)alloc((size_t)KVD * DIM * 2);
  short* wvT = (short*)alloc((size_t)KVD * DIM * 2);
  short* woT = (short*)alloc((size_t)DIM * DIM * 2);
  short* qb  = (short*)alloc((size_t)S_LEN * DIM * 2);
  short* kb  = (short*)alloc((size_t)S_LEN * KVD * 2);
  short* vb  = (short*)alloc((size_t)S_LEN * KVD * 2);
  short* ao  = (short*)alloc((size_t)S_LEN * DIM * 2);
  float* ct  = (float*)alloc((size_t)S_LEN * 64 * 4);
  float* st  = (float*)alloc((size_t)S_LEN * 64 * 4);

  rope_tables_k<<<(S_LEN * 64) / 256, 256, 0, stream>>>(ct, st);
  cast_f32_bf16_k<<<(S_LEN * DIM / 4) / 256, 256, 0, stream>>>(x, xb, S_LEN * DIM / 4);
  transpose_cast_k<<<dim3(DIM / 32, DIM / 32), dim3(32, 8), 0, stream>>>(wq, wqT, DIM, DIM);
  transpose_cast_k<<<dim3(KVD / 32, DIM / 32), dim3(32, 8), 0, stream>>>(wk, wkT, DIM, KVD);
  transpose_cast_k<<<dim3(KVD / 32, DIM / 32), dim3(32, 8), 0, stream>>>(wv, wvT, DIM, KVD);
  transpose_cast_k<<<dim3(DIM / 32, DIM / 32), dim3(32, 8), 0, stream>>>(wo, woT, DIM, DIM);

  gemm_bt_k<1><<<dim3(S_LEN / 128, DIM / 128), 256, 0, stream>>>(xb, wqT, qb, S_LEN, DIM, DIM);
  gemm_bt_k<1><<<dim3(S_LEN / 128, KVD / 128), 256, 0, stream>>>(xb, wkT, kb, S_LEN, KVD, DIM);
  gemm_bt_k<1><<<dim3(S_LEN / 128, KVD / 128), 256, 0, stream>>>(xb, wvT, vb, S_LEN, KVD, DIM);

  rope_apply_k<<<(S_LEN * NH * 64) / 256, 256, 0, stream>>>(qb, ct, st, NH);
  rope_apply_k<<<(S_LEN * NKV * 64) / 256, 256, 0, stream>>>(kb, ct, st, NKV);

  attn_k<<<dim3(S_LEN / 64, NH), 256, 0, stream>>>(qb, kb, vb, ao);

  gemm_bt_k<0><<<dim3(S_LEN / 128, DIM / 128), 256, 0, stream>>>(ao, woT, out, S_LEN, DIM, DIM);
}

// Round 2
// 546.466 us; speedup vs baseline: 1.2240x; 1.2240x over previous
//
#include <hip/hip_runtime.h>
#include <hip/hip_bf16.h>
#include <cstdint>
#include <cmath>

#define DIM 4096
#define NH 32
#define NKV 8
#define HD 128
#define S_LEN 2048
#define KVD (NKV * HD)  // 1024
#define SCALE 0.08838834764831845f

typedef __attribute__((ext_vector_type(4))) float f32x4;
typedef __attribute__((ext_vector_type(8))) short short8;

__device__ __forceinline__ short f2bf(float f) {
  union { float f; uint32_t u; } v; v.f = f;
  uint32_t u = v.u;
  u += 0x7fffu + ((u >> 16) & 1u);
  return (short)(u >> 16);
}
__device__ __forceinline__ float bf2f(short b) {
  union { uint32_t u; float f; } v; v.u = ((uint32_t)(uint16_t)b) << 16;
  return v.f;
}

__device__ __forceinline__ void async16(const void* g, void* l) {
  __builtin_amdgcn_global_load_lds(
      (__attribute__((address_space(1))) void*)(g),
      (__attribute__((address_space(3))) void*)(l), 16, 0, 0);
}

// ---------------- small prep kernels ----------------

__global__ void rope_tables_k(float* __restrict__ ct, float* __restrict__ st) {
  const int i = blockIdx.x * blockDim.x + threadIdx.x;
  if (i >= S_LEN * 64) return;
  const int s = i >> 6, d = i & 63;
  const float inv = powf(10000.0f, -(float)(2 * d) / 128.0f);
  const float fr = (float)s * inv;
  ct[i] = cosf(fr);
  st[i] = sinf(fr);
}

__global__ void cast_f32_bf16_k(const float* __restrict__ in, short* __restrict__ out, int n4) {
  const int i = blockIdx.x * blockDim.x + threadIdx.x;
  if (i >= n4) return;
  const float4 v = ((const float4*)in)[i];
  short4 o;
  o.x = f2bf(v.x); o.y = f2bf(v.y); o.z = f2bf(v.z); o.w = f2bf(v.w);
  ((short4*)out)[i] = o;
}

// w: [K][N] f32 row-major  ->  wt: [N][K] bf16 row-major
__global__ void transpose_cast_k(const float* __restrict__ wsrc, short* __restrict__ wt,
                                 int K, int N) {
  __shared__ float tile[32][33];
  const int tx = threadIdx.x, ty = threadIdx.y;
  const int c0 = blockIdx.x * 32, r0 = blockIdx.y * 32;
#pragma unroll
  for (int j = 0; j < 4; ++j)
    tile[ty + j * 8][tx] = wsrc[(size_t)(r0 + ty + j * 8) * N + c0 + tx];
  __syncthreads();
#pragma unroll
  for (int j = 0; j < 4; ++j)
    wt[(size_t)(c0 + ty + j * 8) * K + r0 + tx] = f2bf(tile[tx][ty + j * 8]);
}

// bf16 full transpose: in [R][C] -> out [C][R]
__global__ void transpose_bf16_k(const short* __restrict__ in, short* __restrict__ out,
                                 int R, int C) {
  __shared__ short tile[32][33];
  const int tx = threadIdx.x, ty = threadIdx.y;
  const int c0 = blockIdx.x * 32, r0 = blockIdx.y * 32;
#pragma unroll
  for (int j = 0; j < 4; ++j)
    tile[ty + j * 8][tx] = in[(size_t)(r0 + ty + j * 8) * C + c0 + tx];
  __syncthreads();
#pragma unroll
  for (int j = 0; j < 4; ++j)
    out[(size_t)(c0 + ty + j * 8) * R + r0 + tx] = tile[tx][ty + j * 8];
}

// in-place RoPE on bf16 [S][nheads*HD]; thread handles (d, d+64) pair
__global__ void rope_apply_k(short* __restrict__ xq, const float* __restrict__ ct,
                             const float* __restrict__ st, int nheads) {
  const int i = blockIdx.x * blockDim.x + threadIdx.x;
  const int total = S_LEN * nheads * 64;
  if (i >= total) return;
  const int d = i & 63;
  const int t = i >> 6;
  const int hh = t % nheads;
  const int s = t / nheads;
  short* p = xq + (size_t)s * (nheads * HD) + hh * HD + d;
  const float x1 = bf2f(p[0]);
  const float x2 = bf2f(p[64]);
  const float c = ct[(s << 6) + d];
  const float sn = st[(s << 6) + d];
  p[0]  = f2bf(x1 * c - x2 * sn);
  p[64] = f2bf(x2 * c + x1 * sn);
}

// ---------------- GEMM: C[M][N] = A[M][K] * BT[N][K]^T (bf16 in, fp32 acc) ----------------

template <int OUT_BF16>
__global__ __launch_bounds__(256) void gemm_bt_k(
    const short* __restrict__ A, const short* __restrict__ BT,
    void* __restrict__ Cv, int M, int N, int K) {
  __shared__ __attribute__((aligned(16))) short As[128 * 32];
  __shared__ __attribute__((aligned(16))) short Bs[128 * 32];
  const int tid = threadIdx.x;
  const int w = tid >> 6, l = tid & 63;
  const int m0 = blockIdx.x * 128, n0 = blockIdx.y * 128;
  const int wr = (w >> 1) * 64, wc = (w & 1) * 64;
  const int lrow = l & 15, lk = (l >> 4) << 3;

  f32x4 acc[4][4] = {};

  const int c0 = w * 2;
  for (int k0 = 0; k0 < K; k0 += 32) {
#pragma unroll
    for (int i = 0; i < 2; ++i) {
      const int e = (c0 + i) * 512 + l * 8;  // element index in 128x32 tile
      const int row = e >> 5, kk = e & 31;
      async16(A + (size_t)(m0 + row) * K + k0 + kk, As + e);
      async16(BT + (size_t)(n0 + row) * K + k0 + kk, Bs + e);
    }
    __syncthreads();
    short8 af[4], bfr[4];
#pragma unroll
    for (int m = 0; m < 4; ++m)
      af[m] = *(const short8*)(As + (wr + m * 16 + lrow) * 32 + lk);
#pragma unroll
    for (int n = 0; n < 4; ++n)
      bfr[n] = *(const short8*)(Bs + (wc + n * 16 + lrow) * 32 + lk);
#pragma unroll
    for (int m = 0; m < 4; ++m)
#pragma unroll
      for (int n = 0; n < 4; ++n)
        acc[m][n] = __builtin_amdgcn_mfma_f32_16x16x32_bf16(af[m], bfr[n], acc[m][n], 0, 0, 0);
    __syncthreads();
  }

  const int orow = m0 + wr + ((l >> 4) << 2);
  const int ocol = n0 + wc + lrow;
#pragma unroll
  for (int m = 0; m < 4; ++m)
#pragma unroll
    for (int n = 0; n < 4; ++n)
#pragma unroll
      for (int r = 0; r < 4; ++r) {
        const size_t idx = (size_t)(orow + m * 16 + r) * N + (ocol + n * 16);
        if (OUT_BF16)
          ((short*)Cv)[idx] = f2bf(acc[m][n][r]);
        else
          ((float*)Cv)[idx] = acc[m][n][r];
      }
}

// ---------------- flash attention (causal, GQA 4:1) ----------------
// 512 blocks, 4 waves; block = 128 q-rows (wave = 32), KV tile = 64, dbuf K/V via
// global_load_lds with pre-swizzled source; swapped QK^T (mfma(K,Q)) -> packed P writes.

__global__ __launch_bounds__(256, 2) void attn_k(
    const short* __restrict__ Q, const short* __restrict__ Kc,
    const short* __restrict__ VTg, short* __restrict__ O) {
  __shared__ __attribute__((aligned(16))) short Ks[2][64 * 128];
  __shared__ __attribute__((aligned(16))) short Vt[2][128 * 64];
  __shared__ __attribute__((aligned(16))) short Ps[4][32 * 64];

  const int tid = threadIdx.x;
  const int w = tid >> 6, l = tid & 63;
  const int lrow = l & 15, lg = l >> 4;

  // qt-pairing: co-resident pairs (b, b+256) get qt and 15-qt -> uniform CU load
  int b = blockIdx.x, h, qt;
  if (b < 256) { h = b >> 3; qt = 15 - (b & 7); }
  else { b -= 256; h = b >> 3; qt = b & 7; }
  const int kvh = h >> 2;
  const int qb0 = qt * 128;
  const int qrow0 = qb0 + w * 32;
  const int nkt = 2 * qt + 2;

  // Q fragments (B-operand of swapped QK): lane lrow = q-row, 8 d at lg*8 per 32-chunk
  short8 qf[2][4];
#pragma unroll
  for (int nq = 0; nq < 2; ++nq) {
    const short* qp = Q + (size_t)(qrow0 + nq * 16 + lrow) * DIM + h * HD;
#pragma unroll
    for (int c = 0; c < 4; ++c) qf[nq][c] = *(const short8*)(qp + c * 32 + lg * 8);
  }

  f32x4 o_acc[2][8] = {};
  float m[2] = {-INFINITY, -INFINITY};
  float lsum[2] = {0.f, 0.f};

  // stage: K tile [64][128], V tile [128][64]; linear LDS dest, source chunk
  // pre-permuted by the same XOR the readers apply (involution, rule 21)
  auto stage = [&](int kb, int buf) {
    short* kd = Ks[buf];
    short* vd = Vt[buf];
#pragma unroll
    for (int it = 0; it < 4; ++it) {
      const int e = it * 256 + tid;        // K: 1024 chunks of 8 elems
      const int row = e >> 4, j = e & 15;
      const int jsrc = (j & 8) | ((j ^ row) & 7);
      async16(Kc + (size_t)(kb + row) * KVD + kvh * HD + jsrc * 8, kd + e * 8);
    }
#pragma unroll
    for (int it = 0; it < 4; ++it) {
      const int e = it * 256 + tid;        // V: 1024 chunks
      const int d = e >> 3, j = e & 7;
      const int jsrc = (j ^ d) & 7;
      async16(VTg + (size_t)(kvh * HD + d) * S_LEN + kb + jsrc * 8, vd + e * 8);
    }
  };

  stage(0, 0);
  int cur = 0;

  for (int kt = 0; kt < nkt; ++kt) {
    __syncthreads();  // drains stage(kt) (vmcnt0 before barrier) + syncs buf reuse
    if (kt + 1 < nkt) stage((kt + 1) * 64, cur ^ 1);
    const int kb = kt * 64;

    if (kb <= qrow0 + 31) {  // wave-uniform: skip fully-masked tiles
      const char* ks = (const char*)Ks[cur];
      const char* vt = (const char*)Vt[cur];
      char* psb = (char*)Ps[w];

      // S^T = mfma(K, Q): lane holds q = nq*16+lrow, k = kb + mk*16 + lg*4 + r
      f32x4 stq[4][2] = {};
#pragma unroll
      for (int c = 0; c < 4; ++c) {
#pragma unroll
        for (int mk = 0; mk < 4; ++mk) {
          const short8 kf = *(const short8*)(
              ks + (mk * 16 + lrow) * 256 + (((c * 4 + lg) ^ (lrow & 7)) << 4));
          stq[mk][0] = __builtin_amdgcn_mfma_f32_16x16x32_bf16(kf, qf[0][c], stq[mk][0], 0, 0, 0);
          stq[mk][1] = __builtin_amdgcn_mfma_f32_16x16x32_bf16(kf, qf[1][c], stq[mk][1], 0, 0, 0);
        }
      }

      // scale + causal mask (diagonal band only)
      const bool needmask = (kb + 63 > qrow0);
#pragma unroll
      for (int mk = 0; mk < 4; ++mk)
#pragma unroll
        for (int nq = 0; nq < 2; ++nq)
#pragma unroll
          for (int r = 0; r < 4; ++r) {
            float v = stq[mk][nq][r] * SCALE;
            if (needmask && (kb + mk * 16 + lg * 4 + r > qrow0 + nq * 16 + lrow))
              v = -INFINITY;
            stq[mk][nq][r] = v;
          }

      // row max (in-lane 16 + shfl over lg groups)
      float vmax[2];
#pragma unroll
      for (int nq = 0; nq < 2; ++nq) {
        float v = stq[0][nq][0];
#pragma unroll
        for (int mk = 0; mk < 4; ++mk)
#pragma unroll
          for (int r = 0; r < 4; ++r) v = fmaxf(v, stq[mk][nq][r]);
        v = fmaxf(v, __shfl_xor(v, 16));
        v = fmaxf(v, __shfl_xor(v, 32));
        vmax[nq] = v;
      }

      // T13 defer-max: skip rescale when growth small (P bounded by e^8)
      const int small = (vmax[0] <= m[0] + 8.0f) && (vmax[1] <= m[1] + 8.0f);
      if (!__all(small)) {
        float al[2];
#pragma unroll
        for (int nq = 0; nq < 2; ++nq) {
          const float mn = fmaxf(m[nq], vmax[nq]);
          al[nq] = __expf(m[nq] - mn);
          m[nq] = mn;
          lsum[nq] *= al[nq];
        }
#pragma unroll
        for (int mmq = 0; mmq < 2; ++mmq)
#pragma unroll
          for (int r = 0; r < 4; ++r) {
            const float a = __shfl(al[mmq], lg * 4 + r);
#pragma unroll
            for (int d = 0; d < 8; ++d) o_acc[mmq][d][r] *= a;
          }
      }

      // P = exp(S - m); packed b64 writes (4 consecutive k per lane)
      float rs[2] = {0.f, 0.f};
#pragma unroll
      for (int nq = 0; nq < 2; ++nq) {
#pragma unroll
        for (int mk = 0; mk < 4; ++mk) {
          const float p0 = __expf(stq[mk][nq][0] - m[nq]);
          const float p1 = __expf(stq[mk][nq][1] - m[nq]);
          const float p2 = __expf(stq[mk][nq][2] - m[nq]);
          const float p3 = __expf(stq[mk][nq][3] - m[nq]);
          rs[nq] += (p0 + p1) + (p2 + p3);
          __hip_bfloat16 b0 = __float2bfloat16(p0), b1 = __float2bfloat16(p1);
          __hip_bfloat16 b2 = __float2bfloat16(p2), b3 = __float2bfloat16(p3);
          short4 pk;
          pk.x = *(short*)&b0; pk.y = *(short*)&b1; pk.z = *(short*)&b2; pk.w = *(short*)&b3;
          const int q = nq * 16 + lrow;
          *(short4*)(psb + q * 128 + ((mk * 32 + lg * 8) ^ ((q & 7) << 4))) = pk;
        }
        float r2 = rs[nq];
        r2 += __shfl_xor(r2, 16);
        r2 += __shfl_xor(r2, 32);
        lsum[nq] += r2;
      }

      // O += P V  (A = P rows, B = V^T rows)
#pragma unroll
      for (int cc = 0; cc < 2; ++cc) {
        const int chunk = ((cc * 4 + lg) ^ (lrow & 7)) << 4;
        const short8 pa0 = *(const short8*)(psb + lrow * 128 + chunk);
        const short8 pa1 = *(const short8*)(psb + (16 + lrow) * 128 + chunk);
#pragma unroll
        for (int d = 0; d < 8; ++d) {
          const short8 vf = *(const short8*)(vt + (d * 16 + lrow) * 128 + chunk);
          o_acc[0][d] = __builtin_amdgcn_mfma_f32_16x16x32_bf16(pa0, vf, o_acc[0][d], 0, 0, 0);
          o_acc[1][d] = __builtin_amdgcn_mfma_f32_16x16x32_bf16(pa1, vf, o_acc[1][d], 0, 0, 0);
        }
      }
    }
    cur ^= 1;
  }

  // epilogue: O /= lsum (redistribute 1/l to C-layout lanes), write bf16
  float linv[2] = {1.0f / lsum[0], 1.0f / lsum[1]};
#pragma unroll
  for (int mmq = 0; mmq < 2; ++mmq)
#pragma unroll
    for (int r = 0; r < 4; ++r) {
      const float li = __shfl(linv[mmq], lg * 4 + r);
      short* op = O + (size_t)(qrow0 + mmq * 16 + lg * 4 + r) * DIM + h * HD;
#pragma unroll
      for (int d = 0; d < 8; ++d)
        op[d * 16 + lrow] = f2bf(o_acc[mmq][d][r] * li);
    }
}

// ---------------- launch ----------------

extern "C" void kernel_launch(void* const* d_in, const int* in_sizes, int n_in,
                              void* d_out, int out_size, void* d_ws, size_t ws_size,
                              hipStream_t stream) {
  const float* x  = (const float*)d_in[0];
  const float* wq = (const float*)d_in[1];
  const float* wk = (const float*)d_in[2];
  const float* wv = (const float*)d_in[3];
  const float* wo = (const float*)d_in[4];
  float* out = (float*)d_out;
  (void)in_sizes; (void)n_in; (void)out_size; (void)ws_size;

  char* ws = (char*)d_ws;
  size_t off = 0;
  auto alloc = [&](size_t bytes) -> void* {
    void* p = ws + off;
    off += (bytes + 255) & ~(size_t)255;
    return p;
  };
  short* xb  = (short*)alloc((size_t)S_LEN * DIM * 2);
  short* wqT = (short*)alloc((size_t)DIM * DIM * 2);
  short* wkT = (short*)alloc((size_t)KVD * DIM * 2);
  short* wvT = (short*)alloc((size_t)KVD * DIM * 2);
  short* woT = (short*)alloc((size_t)DIM * DIM * 2);
  short* qb  = (short*)alloc((size_t)S_LEN * DIM * 2);
  short* kb  = (short*)alloc((size_t)S_LEN * KVD * 2);
  short* vb  = (short*)alloc((size_t)S_LEN * KVD * 2);
  short* vtg = (short*)alloc((size_t)KVD * S_LEN * 2);
  short* ao  = (short*)alloc((size_t)S_LEN * DIM * 2);
  float* ct  = (float*)alloc((size_t)S_LEN * 64 * 4);
  float* st  = (float*)alloc((size_t)S_LEN * 64 * 4);

  rope_tables_k<<<(S_LEN * 64) / 256, 256, 0, stream>>>(ct, st);
  cast_f32_bf16_k<<<(S_LEN * DIM / 4) / 256, 256, 0, stream>>>(x, xb, S_LEN * DIM / 4);
  transpose_cast_k<<<dim3(DIM / 32, DIM / 32), dim3(32, 8), 0, stream>>>(wq, wqT, DIM, DIM);
  transpose_cast_k<<<dim3(KVD / 32, DIM / 32), dim3(32, 8), 0, stream>>>(wk, wkT, DIM, KVD);
  transpose_cast_k<<<dim3(KVD / 32, DIM / 32), dim3(32, 8), 0, stream>>>(wv, wvT, DIM, KVD);
  transpose_cast_k<<<dim3(DIM / 32, DIM / 32), dim3(32, 8), 0, stream>>>(wo, woT, DIM, DIM);

  gemm_bt_k<1><<<dim3(S_LEN / 128, DIM / 128), 256, 0, stream>>>(xb, wqT, qb, S_LEN, DIM, DIM);
  gemm_bt_k<1><<<dim3(S_LEN / 128, KVD / 128), 256, 0, stream>>>(xb, wkT, kb, S_LEN, KVD, DIM);
  gemm_bt_k<1><<<dim3(S_LEN / 128, KVD / 128), 256, 0, stream>>>(xb, wvT, vb, S_LEN, KVD, DIM);

  rope_apply_k<<<(S_LEN * NH * 64) / 256, 256, 0, stream>>>(qb, ct, st, NH);
  rope_apply_k<<<(S_LEN * NKV * 64) / 256, 256, 0, stream>>>(kb, ct, st, NKV);

  transpose_bf16_k<<<dim3(KVD / 32, S_LEN / 32), dim3(32, 8), 0, stream>>>(vb, vtg, S_LEN, KVD);

  attn_k<<<dim3(512), 256, 0, stream>>>(qb, kb, vtg, ao);

  gemm_bt_k<0><<<dim3(S_LEN / 128, DIM / 128), 256, 0, stream>>>(ao, woT, out, S_LEN, DIM, DIM);
}

// Round 3
// 392.683 us; speedup vs baseline: 1.7034x; 1.3916x over previous
//
#include <hip/hip_runtime.h>
#include <hip/hip_bf16.h>
#include <cstdint>
#include <cmath>

#define DIM 4096
#define NH 32
#define NKV 8
#define HD 128
#define S_LEN 2048
#define KVD (NKV * HD)   // 1024
#define QS 6144          // fused qkv row stride
#define SCALE 0.08838834764831845f

typedef __attribute__((ext_vector_type(4))) float f32x4;
typedef __attribute__((ext_vector_type(8))) short short8;

__device__ __forceinline__ short f2bf(float f) {
  union { float f; uint32_t u; } v; v.f = f;
  uint32_t u = v.u;
  u += 0x7fffu + ((u >> 16) & 1u);
  return (short)(u >> 16);
}
__device__ __forceinline__ float bf2f(short b) {
  union { uint32_t u; float f; } v; v.u = ((uint32_t)(uint16_t)b) << 16;
  return v.f;
}

__device__ __forceinline__ void async16(const void* g, void* l) {
  __builtin_amdgcn_global_load_lds(
      (__attribute__((address_space(1))) void*)(g),
      (__attribute__((address_space(3))) void*)(l), 16, 0, 0);
}

// ---------------- small prep kernels ----------------

__global__ void rope_tables_k(float* __restrict__ ct, float* __restrict__ st) {
  const int i = blockIdx.x * blockDim.x + threadIdx.x;
  if (i >= S_LEN * 64) return;
  const int s = i >> 6, d = i & 63;
  const float inv = powf(10000.0f, -(float)(2 * d) / 128.0f);
  const float fr = (float)s * inv;
  ct[i] = cosf(fr);
  st[i] = sinf(fr);
}

__global__ void cast_f32_bf16_k(const float* __restrict__ in, short* __restrict__ out, int n4) {
  const int i = blockIdx.x * blockDim.x + threadIdx.x;
  if (i >= n4) return;
  const float4 v = ((const float4*)in)[i];
  short4 o;
  o.x = f2bf(v.x); o.y = f2bf(v.y); o.z = f2bf(v.z); o.w = f2bf(v.w);
  ((short4*)out)[i] = o;
}

// w: [K][N] f32 row-major  ->  wt: [N][K] bf16 row-major
__global__ void transpose_cast_k(const float* __restrict__ wsrc, short* __restrict__ wt,
                                 int K, int N) {
  __shared__ float tile[32][33];
  const int tx = threadIdx.x, ty = threadIdx.y;
  const int c0 = blockIdx.x * 32, r0 = blockIdx.y * 32;
#pragma unroll
  for (int j = 0; j < 4; ++j)
    tile[ty + j * 8][tx] = wsrc[(size_t)(r0 + ty + j * 8) * N + c0 + tx];
  __syncthreads();
#pragma unroll
  for (int j = 0; j < 4; ++j)
    wt[(size_t)(c0 + ty + j * 8) * K + r0 + tx] = f2bf(tile[tx][ty + j * 8]);
}

// bf16 transpose: in [R][C] (row stride ldi) -> out [C][R]
__global__ void transpose_bf16_k(const short* __restrict__ in, short* __restrict__ out,
                                 int R, int C, int ldi) {
  __shared__ short tile[32][33];
  const int tx = threadIdx.x, ty = threadIdx.y;
  const int c0 = blockIdx.x * 32, r0 = blockIdx.y * 32;
#pragma unroll
  for (int j = 0; j < 4; ++j)
    tile[ty + j * 8][tx] = in[(size_t)(r0 + ty + j * 8) * ldi + c0 + tx];
  __syncthreads();
#pragma unroll
  for (int j = 0; j < 4; ++j)
    out[(size_t)(c0 + ty + j * 8) * R + r0 + tx] = tile[tx][ty + j * 8];
}

// in-place RoPE on bf16 [S][*] with row stride ld; thread handles (d, d+64) pair
__global__ void rope_apply_k(short* __restrict__ xq, int ld, const float* __restrict__ ct,
                             const float* __restrict__ st, int nheads) {
  const int i = blockIdx.x * blockDim.x + threadIdx.x;
  const int total = S_LEN * nheads * 64;
  if (i >= total) return;
  const int d = i & 63;
  const int t = i >> 6;
  const int hh = t % nheads;
  const int s = t / nheads;
  short* p = xq + (size_t)s * ld + hh * HD + d;
  const float x1 = bf2f(p[0]);
  const float x2 = bf2f(p[64]);
  const float c = ct[(s << 6) + d];
  const float sn = st[(s << 6) + d];
  p[0]  = f2bf(x1 * c - x2 * sn);
  p[64] = f2bf(x2 * c + x1 * sn);
}

// ---------------- 256x256 8-phase GEMM: C[M][N] = A[M][K] * BT[N][K]^T ----------------
// 8 waves (2M x 4N), BK=64, dbuf LDS (128KB), XOR-swizzled slots, per-phase
// {ds_read quadrant || stage || barrier || MFMA(setprio) || barrier}, XCD-chunked grid.

template <int OUT_BF16>
__global__ __launch_bounds__(512, 2) void gemm256_k(
    const short* __restrict__ A, const short* __restrict__ BT,
    void* __restrict__ Cv, int M, int N, int K) {
  // [buf][A=0/B=1][half][128 rows][64 k]
  __shared__ __attribute__((aligned(16))) short lds[2][2][2][128 * 64];

  const int tid = threadIdx.x;
  const int w = tid >> 6, l = tid & 63;
  const int wr = w >> 2, wc = w & 3;      // wave 2x4
  const int lrow = l & 15, lg = l >> 4;

  // XCD-chunked bijective swizzle (gridDim.x % 8 == 0)
  int bid = blockIdx.x;
  const int cpx = gridDim.x >> 3;
  bid = (bid & 7) * cpx + (bid >> 3);
  const int ntn = N >> 8;
  const int m0 = (bid / ntn) << 8;
  const int n0 = (bid % ntn) << 8;

  // stage one K-tile (kt) into buf: A[256][64] + B[256][64], 8 loads/thread,
  // source slot pre-permuted by the read-side XOR (involution)
  auto stage = [&](int kt, int buf) {
    const int k0 = kt << 6;
#pragma unroll
    for (int ab = 0; ab < 2; ++ab) {
      const short* src = ab ? BT : A;
      const int base0 = ab ? n0 : m0;
#pragma unroll
      for (int half = 0; half < 2; ++half) {
#pragma unroll
        for (int it = 0; it < 2; ++it) {
          const int e = it * 512 + tid;          // 1024 chunks of 16B per half
          const int row = e >> 3, j = e & 7;
          const int jsrc = j ^ (row & 7);
          async16(src + (size_t)(base0 + half * 128 + row) * K + k0 + jsrc * 8,
                  &lds[buf][ab][half][e * 8]);
        }
      }
    }
  };

  f32x4 acc[8][4] = {};

  stage(0, 0);
  __syncthreads();  // drains vmcnt before barrier

  const int KT = K >> 6;
  for (int kt = 0; kt < KT; ++kt) {
    const int buf = kt & 1;
    const short* Ah = &lds[buf][0][wr][0];
    const short* Bh = &lds[buf][1][wc >> 1][0];
    const int brow0 = (wc & 1) * 64;
    short8 bfrag[2][4];

#pragma unroll
    for (int p = 0; p < 4; ++p) {
      // ds_read this quadrant's A frags (rows 2p,2p+1 of the wave's 8)
      short8 afrag[2][2];
#pragma unroll
      for (int mi = 0; mi < 2; ++mi) {
        const int row = (p * 2 + mi) * 16 + lrow;
#pragma unroll
        for (int kk = 0; kk < 2; ++kk)
          afrag[mi][kk] =
              *(const short8*)(Ah + row * 64 + (((kk * 4 + lg) ^ (row & 7)) << 3));
      }
      if (p == 0) {
        // B frags once per K-tile
#pragma unroll
        for (int n = 0; n < 4; ++n) {
          const int row = brow0 + n * 16 + lrow;
#pragma unroll
          for (int kk = 0; kk < 2; ++kk)
            bfrag[kk][n] =
                *(const short8*)(Bh + row * 64 + (((kk * 4 + lg) ^ (row & 7)) << 3));
        }
        // issue next tile's staging early: ~3 phases of MFMA to hide HBM latency
        if (kt + 1 < KT) stage(kt + 1, buf ^ 1);
      }
      __builtin_amdgcn_s_barrier();              // raw: does NOT drain vmcnt
      asm volatile("s_waitcnt lgkmcnt(0)");
      __builtin_amdgcn_s_setprio(1);
#pragma unroll
      for (int kk = 0; kk < 2; ++kk)
#pragma unroll
        for (int mi = 0; mi < 2; ++mi)
#pragma unroll
          for (int n = 0; n < 4; ++n)
            acc[p * 2 + mi][n] = __builtin_amdgcn_mfma_f32_16x16x32_bf16(
                afrag[mi][kk], bfrag[kk][n], acc[p * 2 + mi][n], 0, 0, 0);
      __builtin_amdgcn_s_setprio(0);
      __builtin_amdgcn_s_barrier();
    }
    __syncthreads();  // per-tile drain: all waves' stage loads landed before buf swap
  }

  // epilogue
  const int orow0 = m0 + wr * 128 + lg * 4;
  const int ocol0 = n0 + wc * 64 + lrow;
#pragma unroll
  for (int m = 0; m < 8; ++m)
#pragma unroll
    for (int n = 0; n < 4; ++n)
#pragma unroll
      for (int r = 0; r < 4; ++r) {
        const size_t idx = (size_t)(orow0 + m * 16 + r) * N + (ocol0 + n * 16);
        if (OUT_BF16)
          ((short*)Cv)[idx] = f2bf(acc[m][n][r]);
        else
          ((float*)Cv)[idx] = acc[m][n][r];
      }
}

// ---------------- flash attention (causal, GQA 4:1) ----------------
// 512 blocks, 4 waves; block = 128 q-rows (wave = 32), KV tile = 64, dbuf K/V via
// global_load_lds with pre-swizzled source; swapped QK^T (mfma(K,Q)) -> packed P writes.
// Q/K read from the fused qkv buffer (row stride QS).

__global__ __launch_bounds__(256, 2) void attn_k(
    const short* __restrict__ Q, const short* __restrict__ Kc,
    const short* __restrict__ VTg, short* __restrict__ O) {
  __shared__ __attribute__((aligned(16))) short Ks[2][64 * 128];
  __shared__ __attribute__((aligned(16))) short Vt[2][128 * 64];
  __shared__ __attribute__((aligned(16))) short Ps[4][32 * 64];

  const int tid = threadIdx.x;
  const int w = tid >> 6, l = tid & 63;
  const int lrow = l & 15, lg = l >> 4;

  // qt-pairing: co-resident pairs (b, b+256) get qt and 15-qt -> uniform CU load
  int b = blockIdx.x, h, qt;
  if (b < 256) { h = b >> 3; qt = 15 - (b & 7); }
  else { b -= 256; h = b >> 3; qt = b & 7; }
  const int kvh = h >> 2;
  const int qb0 = qt * 128;
  const int qrow0 = qb0 + w * 32;
  const int nkt = 2 * qt + 2;

  // Q fragments (B-operand of swapped QK): lane lrow = q-row, 8 d at lg*8 per 32-chunk
  short8 qf[2][4];
#pragma unroll
  for (int nq = 0; nq < 2; ++nq) {
    const short* qp = Q + (size_t)(qrow0 + nq * 16 + lrow) * QS + h * HD;
#pragma unroll
    for (int c = 0; c < 4; ++c) qf[nq][c] = *(const short8*)(qp + c * 32 + lg * 8);
  }

  f32x4 o_acc[2][8] = {};
  float m[2] = {-INFINITY, -INFINITY};
  float lsum[2] = {0.f, 0.f};

  auto stage = [&](int kb, int buf) {
    short* kd = Ks[buf];
    short* vd = Vt[buf];
#pragma unroll
    for (int it = 0; it < 4; ++it) {
      const int e = it * 256 + tid;        // K: 1024 chunks of 8 elems
      const int row = e >> 4, j = e & 15;
      const int jsrc = (j & 8) | ((j ^ row) & 7);
      async16(Kc + (size_t)(kb + row) * QS + kvh * HD + jsrc * 8, kd + e * 8);
    }
#pragma unroll
    for (int it = 0; it < 4; ++it) {
      const int e = it * 256 + tid;        // V: 1024 chunks
      const int d = e >> 3, j = e & 7;
      const int jsrc = (j ^ d) & 7;
      async16(VTg + (size_t)(kvh * HD + d) * S_LEN + kb + jsrc * 8, vd + e * 8);
    }
  };

  stage(0, 0);
  int cur = 0;

  for (int kt = 0; kt < nkt; ++kt) {
    __syncthreads();  // drains stage(kt) (vmcnt0 before barrier) + syncs buf reuse
    if (kt + 1 < nkt) stage((kt + 1) * 64, cur ^ 1);
    const int kb = kt * 64;

    if (kb <= qrow0 + 31) {  // wave-uniform: skip fully-masked tiles
      const char* ks = (const char*)Ks[cur];
      const char* vt = (const char*)Vt[cur];
      char* psb = (char*)Ps[w];

      // S^T = mfma(K, Q): lane holds q = nq*16+lrow, k = kb + mk*16 + lg*4 + r
      f32x4 stq[4][2] = {};
#pragma unroll
      for (int c = 0; c < 4; ++c) {
#pragma unroll
        for (int mk = 0; mk < 4; ++mk) {
          const short8 kf = *(const short8*)(
              ks + (mk * 16 + lrow) * 256 + (((c * 4 + lg) ^ (lrow & 7)) << 4));
          stq[mk][0] = __builtin_amdgcn_mfma_f32_16x16x32_bf16(kf, qf[0][c], stq[mk][0], 0, 0, 0);
          stq[mk][1] = __builtin_amdgcn_mfma_f32_16x16x32_bf16(kf, qf[1][c], stq[mk][1], 0, 0, 0);
        }
      }

      // scale + causal mask (diagonal band only)
      const bool needmask = (kb + 63 > qrow0);
#pragma unroll
      for (int mk = 0; mk < 4; ++mk)
#pragma unroll
        for (int nq = 0; nq < 2; ++nq)
#pragma unroll
          for (int r = 0; r < 4; ++r) {
            float v = stq[mk][nq][r] * SCALE;
            if (needmask && (kb + mk * 16 + lg * 4 + r > qrow0 + nq * 16 + lrow))
              v = -INFINITY;
            stq[mk][nq][r] = v;
          }

      // row max (in-lane 16 + shfl over lg groups)
      float vmax[2];
#pragma unroll
      for (int nq = 0; nq < 2; ++nq) {
        float v = stq[0][nq][0];
#pragma unroll
        for (int mk = 0; mk < 4; ++mk)
#pragma unroll
          for (int r = 0; r < 4; ++r) v = fmaxf(v, stq[mk][nq][r]);
        v = fmaxf(v, __shfl_xor(v, 16));
        v = fmaxf(v, __shfl_xor(v, 32));
        vmax[nq] = v;
      }

      // T13 defer-max: skip rescale when growth small (P bounded by e^8)
      const int small = (vmax[0] <= m[0] + 8.0f) && (vmax[1] <= m[1] + 8.0f);
      if (!__all(small)) {
        float al[2];
#pragma unroll
        for (int nq = 0; nq < 2; ++nq) {
          const float mn = fmaxf(m[nq], vmax[nq]);
          al[nq] = __expf(m[nq] - mn);
          m[nq] = mn;
          lsum[nq] *= al[nq];
        }
#pragma unroll
        for (int mmq = 0; mmq < 2; ++mmq)
#pragma unroll
          for (int r = 0; r < 4; ++r) {
            const float a = __shfl(al[mmq], lg * 4 + r);
#pragma unroll
            for (int d = 0; d < 8; ++d) o_acc[mmq][d][r] *= a;
          }
      }

      // P = exp(S - m); packed b64 writes (4 consecutive k per lane)
      float rs[2] = {0.f, 0.f};
#pragma unroll
      for (int nq = 0; nq < 2; ++nq) {
#pragma unroll
        for (int mk = 0; mk < 4; ++mk) {
          const float p0 = __expf(stq[mk][nq][0] - m[nq]);
          const float p1 = __expf(stq[mk][nq][1] - m[nq]);
          const float p2 = __expf(stq[mk][nq][2] - m[nq]);
          const float p3 = __expf(stq[mk][nq][3] - m[nq]);
          rs[nq] += (p0 + p1) + (p2 + p3);
          __hip_bfloat16 b0 = __float2bfloat16(p0), b1 = __float2bfloat16(p1);
          __hip_bfloat16 b2 = __float2bfloat16(p2), b3 = __float2bfloat16(p3);
          short4 pk;
          pk.x = *(short*)&b0; pk.y = *(short*)&b1; pk.z = *(short*)&b2; pk.w = *(short*)&b3;
          const int q = nq * 16 + lrow;
          *(short4*)(psb + q * 128 + ((mk * 32 + lg * 8) ^ ((q & 7) << 4))) = pk;
        }
        float r2 = rs[nq];
        r2 += __shfl_xor(r2, 16);
        r2 += __shfl_xor(r2, 32);
        lsum[nq] += r2;
      }

      // O += P V  (A = P rows, B = V^T rows)
#pragma unroll
      for (int cc = 0; cc < 2; ++cc) {
        const int chunk = ((cc * 4 + lg) ^ (lrow & 7)) << 4;
        const short8 pa0 = *(const short8*)(psb + lrow * 128 + chunk);
        const short8 pa1 = *(const short8*)(psb + (16 + lrow) * 128 + chunk);
#pragma unroll
        for (int d = 0; d < 8; ++d) {
          const short8 vf = *(const short8*)(vt + (d * 16 + lrow) * 128 + chunk);
          o_acc[0][d] = __builtin_amdgcn_mfma_f32_16x16x32_bf16(pa0, vf, o_acc[0][d], 0, 0, 0);
          o_acc[1][d] = __builtin_amdgcn_mfma_f32_16x16x32_bf16(pa1, vf, o_acc[1][d], 0, 0, 0);
        }
      }
    }
    cur ^= 1;
  }

  // epilogue: O /= lsum (redistribute 1/l to C-layout lanes), write bf16
  float linv[2] = {1.0f / lsum[0], 1.0f / lsum[1]};
#pragma unroll
  for (int mmq = 0; mmq < 2; ++mmq)
#pragma unroll
    for (int r = 0; r < 4; ++r) {
      const float li = __shfl(linv[mmq], lg * 4 + r);
      short* op = O + (size_t)(qrow0 + mmq * 16 + lg * 4 + r) * DIM + h * HD;
#pragma unroll
      for (int d = 0; d < 8; ++d)
        op[d * 16 + lrow] = f2bf(o_acc[mmq][d][r] * li);
    }
}

// ---------------- launch ----------------

extern "C" void kernel_launch(void* const* d_in, const int* in_sizes, int n_in,
                              void* d_out, int out_size, void* d_ws, size_t ws_size,
                              hipStream_t stream) {
  const float* x  = (const float*)d_in[0];
  const float* wq = (const float*)d_in[1];
  const float* wk = (const float*)d_in[2];
  const float* wv = (const float*)d_in[3];
  const float* wo = (const float*)d_in[4];
  float* out = (float*)d_out;
  (void)in_sizes; (void)n_in; (void)out_size; (void)ws_size;

  char* ws = (char*)d_ws;
  size_t off = 0;
  auto alloc = [&](size_t bytes) -> void* {
    void* p = ws + off;
    off += (bytes + 255) & ~(size_t)255;
    return p;
  };
  short* xb     = (short*)alloc((size_t)S_LEN * DIM * 2);
  short* wqkvT  = (short*)alloc((size_t)QS * DIM * 2);     // [6144][4096]
  short* woT    = (short*)alloc((size_t)DIM * DIM * 2);
  short* qkv    = (short*)alloc((size_t)S_LEN * QS * 2);   // [2048][6144]
  short* vtg    = (short*)alloc((size_t)KVD * S_LEN * 2);  // [1024][2048]
  short* ao     = (short*)alloc((size_t)S_LEN * DIM * 2);
  float* ct     = (float*)alloc((size_t)S_LEN * 64 * 4);
  float* st     = (float*)alloc((size_t)S_LEN * 64 * 4);

  rope_tables_k<<<(S_LEN * 64) / 256, 256, 0, stream>>>(ct, st);
  cast_f32_bf16_k<<<(S_LEN * DIM / 4) / 256, 256, 0, stream>>>(x, xb, S_LEN * DIM / 4);
  // fused W: rows 0..4095 = wq^T, 4096..5119 = wk^T, 5120..6143 = wv^T
  transpose_cast_k<<<dim3(DIM / 32, DIM / 32), dim3(32, 8), 0, stream>>>(wq, wqkvT, DIM, DIM);
  transpose_cast_k<<<dim3(KVD / 32, DIM / 32), dim3(32, 8), 0, stream>>>(
      wk, wqkvT + (size_t)4096 * DIM, DIM, KVD);
  transpose_cast_k<<<dim3(KVD / 32, DIM / 32), dim3(32, 8), 0, stream>>>(
      wv, wqkvT + (size_t)5120 * DIM, DIM, KVD);
  transpose_cast_k<<<dim3(DIM / 32, DIM / 32), dim3(32, 8), 0, stream>>>(wo, woT, DIM, DIM);

  // fused QKV projection: [2048][6144]
  gemm256_k<1><<<dim3((S_LEN / 256) * (QS / 256)), 512, 0, stream>>>(
      xb, wqkvT, qkv, S_LEN, QS, DIM);

  rope_apply_k<<<(S_LEN * NH * 64) / 256, 256, 0, stream>>>(qkv, QS, ct, st, NH);
  rope_apply_k<<<(S_LEN * NKV * 64) / 256, 256, 0, stream>>>(qkv + 4096, QS, ct, st, NKV);

  // V^T: [1024][2048] from qkv cols 5120..6143
  transpose_bf16_k<<<dim3(KVD / 32, S_LEN / 32), dim3(32, 8), 0, stream>>>(
      qkv + 5120, vtg, S_LEN, KVD, QS);

  attn_k<<<dim3(512), 256, 0, stream>>>(qkv, qkv + 4096, vtg, ao);

  gemm256_k<0><<<dim3((S_LEN / 256) * (DIM / 256)), 512, 0, stream>>>(
      ao, woT, out, S_LEN, DIM, DIM);
}

// Round 4
// 372.808 us; speedup vs baseline: 1.7942x; 1.0533x over previous
//
#include <hip/hip_runtime.h>
#include <hip/hip_bf16.h>
#include <cstdint>
#include <cmath>

#define DIM 4096
#define NH 32
#define NKV 8
#define HD 128
#define S_LEN 2048
#define KVD (NKV * HD)   // 1024
#define QS 6144          // fused qkv row stride
#define SCALE 0.08838834764831845f

typedef __attribute__((ext_vector_type(4))) float f32x4;
typedef __attribute__((ext_vector_type(8))) short short8;

__device__ __forceinline__ short f2bf(float f) {
  union { float f; uint32_t u; } v; v.f = f;
  uint32_t u = v.u;
  u += 0x7fffu + ((u >> 16) & 1u);
  return (short)(u >> 16);
}
__device__ __forceinline__ float bf2f(short b) {
  union { uint32_t u; float f; } v; v.u = ((uint32_t)(uint16_t)b) << 16;
  return v.f;
}

__device__ __forceinline__ void async16(const void* g, void* l) {
  __builtin_amdgcn_global_load_lds(
      (__attribute__((address_space(1))) void*)(g),
      (__attribute__((address_space(3))) void*)(l), 16, 0, 0);
}

// ---------------- small prep kernels ----------------

__global__ void rope_tables_k(float* __restrict__ ct, float* __restrict__ st) {
  const int i = blockIdx.x * blockDim.x + threadIdx.x;
  if (i >= S_LEN * 64) return;
  const int s = i >> 6, d = i & 63;
  const float inv = powf(10000.0f, -(float)(2 * d) / 128.0f);
  const float fr = (float)s * inv;
  ct[i] = cosf(fr);
  st[i] = sinf(fr);
}

__global__ void cast_f32_bf16_k(const float* __restrict__ in, short* __restrict__ out, int n4) {
  const int i = blockIdx.x * blockDim.x + threadIdx.x;
  if (i >= n4) return;
  const float4 v = ((const float4*)in)[i];
  short4 o;
  o.x = f2bf(v.x); o.y = f2bf(v.y); o.z = f2bf(v.z); o.w = f2bf(v.w);
  ((short4*)out)[i] = o;
}

// w: [K][N] f32 row-major  ->  wt: [N][K] bf16 row-major
__global__ void transpose_cast_k(const float* __restrict__ wsrc, short* __restrict__ wt,
                                 int K, int N) {
  __shared__ float tile[32][33];
  const int tx = threadIdx.x, ty = threadIdx.y;
  const int c0 = blockIdx.x * 32, r0 = blockIdx.y * 32;
#pragma unroll
  for (int j = 0; j < 4; ++j)
    tile[ty + j * 8][tx] = wsrc[(size_t)(r0 + ty + j * 8) * N + c0 + tx];
  __syncthreads();
#pragma unroll
  for (int j = 0; j < 4; ++j)
    wt[(size_t)(c0 + ty + j * 8) * K + r0 + tx] = f2bf(tile[tx][ty + j * 8]);
}

// bf16 transpose: in [R][C] (row stride ldi) -> out [C][R]
__global__ void transpose_bf16_k(const short* __restrict__ in, short* __restrict__ out,
                                 int R, int C, int ldi) {
  __shared__ short tile[32][33];
  const int tx = threadIdx.x, ty = threadIdx.y;
  const int c0 = blockIdx.x * 32, r0 = blockIdx.y * 32;
#pragma unroll
  for (int j = 0; j < 4; ++j)
    tile[ty + j * 8][tx] = in[(size_t)(r0 + ty + j * 8) * ldi + c0 + tx];
  __syncthreads();
#pragma unroll
  for (int j = 0; j < 4; ++j)
    out[(size_t)(c0 + ty + j * 8) * R + r0 + tx] = tile[tx][ty + j * 8];
}

// in-place RoPE on bf16 [S][*] with row stride ld; thread handles (d, d+64) pair
__global__ void rope_apply_k(short* __restrict__ xq, int ld, const float* __restrict__ ct,
                             const float* __restrict__ st, int nheads) {
  const int i = blockIdx.x * blockDim.x + threadIdx.x;
  const int total = S_LEN * nheads * 64;
  if (i >= total) return;
  const int d = i & 63;
  const int t = i >> 6;
  const int hh = t % nheads;
  const int s = t / nheads;
  short* p = xq + (size_t)s * ld + hh * HD + d;
  const float x1 = bf2f(p[0]);
  const float x2 = bf2f(p[64]);
  const float c = ct[(s << 6) + d];
  const float sn = st[(s << 6) + d];
  p[0]  = f2bf(x1 * c - x2 * sn);
  p[64] = f2bf(x2 * c + x1 * sn);
}

// ---------------- pipelined GEMM: C[M][N] = A[M][K] * BT[N][K]^T ----------------
// BN=256 fixed, BK=64, 512 threads (8 waves, 2M x 4N). Template BM (256 or 128),
// NBUF-deep LDS ring with counted vmcnt (T3+T4): tile-boundary wait = vmcnt(J*L),
// never 0 in steady state. Raw s_barrier; stage(kt+NBUF) issued after all waves'
// lgkmcnt(0) of tile kt (phase NP-1 second barrier) -> buffer reuse race-free.

template <int BM, int NBUF, int OUT_BF16>
__global__ __launch_bounds__(512, 2) void gemm_p(
    const short* __restrict__ A, const short* __restrict__ BT,
    void* __restrict__ Cv, int M, int N, int K) {
  constexpr int TILE = (BM + 256) * 64;        // shorts per buffer
  constexpr int LA = BM / 64;                  // A loads/thread
  constexpr int L = LA + 4;                    // loads/thread/tile
  constexpr int NP = BM / 64;                  // phases (2 A-rows each)
  __shared__ __attribute__((aligned(16))) short lds[NBUF][TILE];

  const int tid = threadIdx.x;
  const int w = tid >> 6, l = tid & 63;
  const int wr = w >> 2, wc = w & 3;
  const int lrow = l & 15, lg = l >> 4;

  // XCD-chunked bijective swizzle (gridDim.x % 8 == 0)
  int bid = blockIdx.x;
  const int cpx = gridDim.x >> 3;
  bid = (bid & 7) * cpx + (bid >> 3);
  const int ntn = N >> 8;
  const int m0 = (bid / ntn) * BM;
  const int n0 = (bid % ntn) << 8;

  auto stage = [&](int kt, int buf) {
    const int k0 = kt << 6;
    short* dst = &lds[buf][0];
#pragma unroll
    for (int it = 0; it < LA; ++it) {
      const int e = it * 512 + tid;
      const int row = e >> 3, j = e & 7;
      const int jsrc = j ^ (row & 7);
      async16(A + (size_t)(m0 + row) * K + k0 + jsrc * 8, dst + e * 8);
    }
#pragma unroll
    for (int it = 0; it < 4; ++it) {
      const int e = it * 512 + tid;
      const int row = e >> 3, j = e & 7;
      const int jsrc = j ^ (row & 7);
      async16(BT + (size_t)(n0 + row) * K + k0 + jsrc * 8, dst + BM * 64 + e * 8);
    }
  };

  auto vwait = [&](int J) {  // wait until only J tiles' loads remain in flight
    if constexpr (BM == 256) {
      if (J >= 1) asm volatile("s_waitcnt vmcnt(8)" ::: "memory");
      else        asm volatile("s_waitcnt vmcnt(0)" ::: "memory");
    } else {
      if (J >= 2)      asm volatile("s_waitcnt vmcnt(12)" ::: "memory");
      else if (J == 1) asm volatile("s_waitcnt vmcnt(6)" ::: "memory");
      else             asm volatile("s_waitcnt vmcnt(0)" ::: "memory");
    }
  };

  f32x4 acc[NP * 2][4] = {};

  const int KT = K >> 6;
  // prologue: fill the ring
#pragma unroll
  for (int t = 0; t < NBUF; ++t) stage(t, t);
  vwait(NBUF - 1);
  __builtin_amdgcn_s_barrier();

  for (int kt = 0; kt < KT; ++kt) {
    const int buf = kt % NBUF;
    const short* Ah = &lds[buf][0];
    const short* Bh = &lds[buf][BM * 64];
    short8 bfrag[2][4];

#pragma unroll
    for (int p = 0; p < NP; ++p) {
      short8 afrag[2][2];
#pragma unroll
      for (int mi = 0; mi < 2; ++mi) {
        const int row = wr * (BM / 2) + (p * 2 + mi) * 16 + lrow;
#pragma unroll
        for (int kk = 0; kk < 2; ++kk)
          afrag[mi][kk] =
              *(const short8*)(Ah + row * 64 + (((kk * 4 + lg) ^ (row & 7)) << 3));
      }
      if (p == 0) {
#pragma unroll
        for (int n = 0; n < 4; ++n) {
          const int row = wc * 64 + n * 16 + lrow;
#pragma unroll
          for (int kk = 0; kk < 2; ++kk)
            bfrag[kk][n] =
                *(const short8*)(Bh + row * 64 + (((kk * 4 + lg) ^ (row & 7)) << 3));
        }
      }
      __builtin_amdgcn_s_barrier();
      asm volatile("s_waitcnt lgkmcnt(0)" ::: "memory");
      __builtin_amdgcn_s_setprio(1);
#pragma unroll
      for (int kk = 0; kk < 2; ++kk)
#pragma unroll
        for (int mi = 0; mi < 2; ++mi)
#pragma unroll
          for (int n = 0; n < 4; ++n)
            acc[p * 2 + mi][n] = __builtin_amdgcn_mfma_f32_16x16x32_bf16(
                afrag[mi][kk], bfrag[kk][n], acc[p * 2 + mi][n], 0, 0, 0);
      __builtin_amdgcn_s_setprio(0);
      __builtin_amdgcn_s_barrier();
    }
    // tile kt fully read by all waves -> safe to overwrite its buffer
    if (kt + 1 < KT) {
      const int nst = kt + NBUF;
      if (nst < KT) stage(nst, buf);
      const int J = (nst < KT ? nst : KT - 1) - (kt + 1);
      vwait(J);
      __builtin_amdgcn_s_barrier();
    }
  }

  // epilogue
  const int orow0 = m0 + wr * (BM / 2) + lg * 4;
  const int ocol0 = n0 + wc * 64 + lrow;
#pragma unroll
  for (int m = 0; m < NP * 2; ++m)
#pragma unroll
    for (int n = 0; n < 4; ++n)
#pragma unroll
      for (int r = 0; r < 4; ++r) {
        const size_t idx = (size_t)(orow0 + m * 16 + r) * N + (ocol0 + n * 16);
        if (OUT_BF16)
          ((short*)Cv)[idx] = f2bf(acc[m][n][r]);
        else
          ((float*)Cv)[idx] = acc[m][n][r];
      }
}

// ---------------- flash attention (causal, GQA 4:1) ----------------

__global__ __launch_bounds__(256, 2) void attn_k(
    const short* __restrict__ Q, const short* __restrict__ Kc,
    const short* __restrict__ VTg, short* __restrict__ O) {
  __shared__ __attribute__((aligned(16))) short Ks[2][64 * 128];
  __shared__ __attribute__((aligned(16))) short Vt[2][128 * 64];
  __shared__ __attribute__((aligned(16))) short Ps[4][32 * 64];

  const int tid = threadIdx.x;
  const int w = tid >> 6, l = tid & 63;
  const int lrow = l & 15, lg = l >> 4;

  int b = blockIdx.x, h, qt;
  if (b < 256) { h = b >> 3; qt = 15 - (b & 7); }
  else { b -= 256; h = b >> 3; qt = b & 7; }
  const int kvh = h >> 2;
  const int qb0 = qt * 128;
  const int qrow0 = qb0 + w * 32;
  const int nkt = 2 * qt + 2;

  short8 qf[2][4];
#pragma unroll
  for (int nq = 0; nq < 2; ++nq) {
    const short* qp = Q + (size_t)(qrow0 + nq * 16 + lrow) * QS + h * HD;
#pragma unroll
    for (int c = 0; c < 4; ++c) qf[nq][c] = *(const short8*)(qp + c * 32 + lg * 8);
  }

  f32x4 o_acc[2][8] = {};
  float m[2] = {-INFINITY, -INFINITY};
  float lsum[2] = {0.f, 0.f};

  auto stage = [&](int kb, int buf) {
    short* kd = Ks[buf];
    short* vd = Vt[buf];
#pragma unroll
    for (int it = 0; it < 4; ++it) {
      const int e = it * 256 + tid;
      const int row = e >> 4, j = e & 15;
      const int jsrc = (j & 8) | ((j ^ row) & 7);
      async16(Kc + (size_t)(kb + row) * QS + kvh * HD + jsrc * 8, kd + e * 8);
    }
#pragma unroll
    for (int it = 0; it < 4; ++it) {
      const int e = it * 256 + tid;
      const int d = e >> 3, j = e & 7;
      const int jsrc = (j ^ d) & 7;
      async16(VTg + (size_t)(kvh * HD + d) * S_LEN + kb + jsrc * 8, vd + e * 8);
    }
  };

  stage(0, 0);
  int cur = 0;

  for (int kt = 0; kt < nkt; ++kt) {
    __syncthreads();
    if (kt + 1 < nkt) stage((kt + 1) * 64, cur ^ 1);
    const int kb = kt * 64;

    if (kb <= qrow0 + 31) {
      const char* ks = (const char*)Ks[cur];
      const char* vt = (const char*)Vt[cur];
      char* psb = (char*)Ps[w];

      f32x4 stq[4][2] = {};
#pragma unroll
      for (int c = 0; c < 4; ++c) {
#pragma unroll
        for (int mk = 0; mk < 4; ++mk) {
          const short8 kf = *(const short8*)(
              ks + (mk * 16 + lrow) * 256 + (((c * 4 + lg) ^ (lrow & 7)) << 4));
          stq[mk][0] = __builtin_amdgcn_mfma_f32_16x16x32_bf16(kf, qf[0][c], stq[mk][0], 0, 0, 0);
          stq[mk][1] = __builtin_amdgcn_mfma_f32_16x16x32_bf16(kf, qf[1][c], stq[mk][1], 0, 0, 0);
        }
      }

      const bool needmask = (kb + 63 > qrow0);
#pragma unroll
      for (int mk = 0; mk < 4; ++mk)
#pragma unroll
        for (int nq = 0; nq < 2; ++nq)
#pragma unroll
          for (int r = 0; r < 4; ++r) {
            float v = stq[mk][nq][r] * SCALE;
            if (needmask && (kb + mk * 16 + lg * 4 + r > qrow0 + nq * 16 + lrow))
              v = -INFINITY;
            stq[mk][nq][r] = v;
          }

      float vmax[2];
#pragma unroll
      for (int nq = 0; nq < 2; ++nq) {
        float v = stq[0][nq][0];
#pragma unroll
        for (int mk = 0; mk < 4; ++mk)
#pragma unroll
          for (int r = 0; r < 4; ++r) v = fmaxf(v, stq[mk][nq][r]);
        v = fmaxf(v, __shfl_xor(v, 16));
        v = fmaxf(v, __shfl_xor(v, 32));
        vmax[nq] = v;
      }

      const int small = (vmax[0] <= m[0] + 8.0f) && (vmax[1] <= m[1] + 8.0f);
      if (!__all(small)) {
        float al[2];
#pragma unroll
        for (int nq = 0; nq < 2; ++nq) {
          const float mn = fmaxf(m[nq], vmax[nq]);
          al[nq] = __expf(m[nq] - mn);
          m[nq] = mn;
          lsum[nq] *= al[nq];
        }
#pragma unroll
        for (int mmq = 0; mmq < 2; ++mmq)
#pragma unroll
          for (int r = 0; r < 4; ++r) {
            const float a = __shfl(al[mmq], lg * 4 + r);
#pragma unroll
            for (int d = 0; d < 8; ++d) o_acc[mmq][d][r] *= a;
          }
      }

      float rs[2] = {0.f, 0.f};
#pragma unroll
      for (int nq = 0; nq < 2; ++nq) {
#pragma unroll
        for (int mk = 0; mk < 4; ++mk) {
          const float p0 = __expf(stq[mk][nq][0] - m[nq]);
          const float p1 = __expf(stq[mk][nq][1] - m[nq]);
          const float p2 = __expf(stq[mk][nq][2] - m[nq]);
          const float p3 = __expf(stq[mk][nq][3] - m[nq]);
          rs[nq] += (p0 + p1) + (p2 + p3);
          __hip_bfloat16 b0 = __float2bfloat16(p0), b1 = __float2bfloat16(p1);
          __hip_bfloat16 b2 = __float2bfloat16(p2), b3 = __float2bfloat16(p3);
          short4 pk;
          pk.x = *(short*)&b0; pk.y = *(short*)&b1; pk.z = *(short*)&b2; pk.w = *(short*)&b3;
          const int q = nq * 16 + lrow;
          *(short4*)(psb + q * 128 + ((mk * 32 + lg * 8) ^ ((q & 7) << 4))) = pk;
        }
        float r2 = rs[nq];
        r2 += __shfl_xor(r2, 16);
        r2 += __shfl_xor(r2, 32);
        lsum[nq] += r2;
      }

#pragma unroll
      for (int cc = 0; cc < 2; ++cc) {
        const int chunk = ((cc * 4 + lg) ^ (lrow & 7)) << 4;
        const short8 pa0 = *(const short8*)(psb + lrow * 128 + chunk);
        const short8 pa1 = *(const short8*)(psb + (16 + lrow) * 128 + chunk);
#pragma unroll
        for (int d = 0; d < 8; ++d) {
          const short8 vf = *(const short8*)(vt + (d * 16 + lrow) * 128 + chunk);
          o_acc[0][d] = __builtin_amdgcn_mfma_f32_16x16x32_bf16(pa0, vf, o_acc[0][d], 0, 0, 0);
          o_acc[1][d] = __builtin_amdgcn_mfma_f32_16x16x32_bf16(pa1, vf, o_acc[1][d], 0, 0, 0);
        }
      }
    }
    cur ^= 1;
  }

  float linv[2] = {1.0f / lsum[0], 1.0f / lsum[1]};
#pragma unroll
  for (int mmq = 0; mmq < 2; ++mmq)
#pragma unroll
    for (int r = 0; r < 4; ++r) {
      const float li = __shfl(linv[mmq], lg * 4 + r);
      short* op = O + (size_t)(qrow0 + mmq * 16 + lg * 4 + r) * DIM + h * HD;
#pragma unroll
      for (int d = 0; d < 8; ++d)
        op[d * 16 + lrow] = f2bf(o_acc[mmq][d][r] * li);
    }
}

// ---------------- launch ----------------

extern "C" void kernel_launch(void* const* d_in, const int* in_sizes, int n_in,
                              void* d_out, int out_size, void* d_ws, size_t ws_size,
                              hipStream_t stream) {
  const float* x  = (const float*)d_in[0];
  const float* wq = (const float*)d_in[1];
  const float* wk = (const float*)d_in[2];
  const float* wv = (const float*)d_in[3];
  const float* wo = (const float*)d_in[4];
  float* out = (float*)d_out;
  (void)in_sizes; (void)n_in; (void)out_size; (void)ws_size;

  char* ws = (char*)d_ws;
  size_t off = 0;
  auto alloc = [&](size_t bytes) -> void* {
    void* p = ws + off;
    off += (bytes + 255) & ~(size_t)255;
    return p;
  };
  short* xb     = (short*)alloc((size_t)S_LEN * DIM * 2);
  short* wqkvT  = (short*)alloc((size_t)QS * DIM * 2);     // [6144][4096]
  short* woT    = (short*)alloc((size_t)DIM * DIM * 2);
  short* qkv    = (short*)alloc((size_t)S_LEN * QS * 2);   // [2048][6144]
  short* vtg    = (short*)alloc((size_t)KVD * S_LEN * 2);  // [1024][2048]
  short* ao     = (short*)alloc((size_t)S_LEN * DIM * 2);
  float* ct     = (float*)alloc((size_t)S_LEN * 64 * 4);
  float* st     = (float*)alloc((size_t)S_LEN * 64 * 4);

  rope_tables_k<<<(S_LEN * 64) / 256, 256, 0, stream>>>(ct, st);
  cast_f32_bf16_k<<<(S_LEN * DIM / 4) / 256, 256, 0, stream>>>(x, xb, S_LEN * DIM / 4);
  transpose_cast_k<<<dim3(DIM / 32, DIM / 32), dim3(32, 8), 0, stream>>>(wq, wqkvT, DIM, DIM);
  transpose_cast_k<<<dim3(KVD / 32, DIM / 32), dim3(32, 8), 0, stream>>>(
      wk, wqkvT + (size_t)4096 * DIM, DIM, KVD);
  transpose_cast_k<<<dim3(KVD / 32, DIM / 32), dim3(32, 8), 0, stream>>>(
      wv, wqkvT + (size_t)5120 * DIM, DIM, KVD);
  transpose_cast_k<<<dim3(DIM / 32, DIM / 32), dim3(32, 8), 0, stream>>>(wo, woT, DIM, DIM);

  // fused QKV projection: [2048][6144], 256x256 tiles, 192 blocks
  gemm_p<256, 2, 1><<<dim3((S_LEN / 256) * (QS / 256)), 512, 0, stream>>>(
      xb, wqkvT, qkv, S_LEN, QS, DIM);

  rope_apply_k<<<(S_LEN * NH * 64) / 256, 256, 0, stream>>>(qkv, QS, ct, st, NH);
  rope_apply_k<<<(S_LEN * NKV * 64) / 256, 256, 0, stream>>>(qkv + 4096, QS, ct, st, NKV);

  transpose_bf16_k<<<dim3(KVD / 32, S_LEN / 32), dim3(32, 8), 0, stream>>>(
      qkv + 5120, vtg, S_LEN, KVD, QS);

  attn_k<<<dim3(512), 256, 0, stream>>>(qkv, qkv + 4096, vtg, ao);

  // output projection: 128x256 tiles -> 256 blocks (full machine), depth-3 pipeline
  gemm_p<128, 3, 0><<<dim3((S_LEN / 128) * (DIM / 256)), 512, 0, stream>>>(
      ao, woT, out, S_LEN, DIM, DIM);
}